// Round 8
// baseline (3437.302 us; speedup 1.0000x reference)
//
#include <hip/hip_runtime.h>

#define NN 2048
#define MM 2048
#define KC 8
#define DD 64
#define RUP(n) (((n)+31)&~31)
#define CPAD (2*NN*MM + NN*NN + MM*MM + 32*2*(NN+MM) + 1024)
#define PADV 3.0e38f
#define LN2F    0.6931471805599453f
#define INVLN2F 1.4426950408889634f
#define DYNB 162816            // dynamic LDS request (159 KB); HW max 160 KB/WG
#define DYNB_FALLBACK 57344    // if big-LDS attribute not honored

// zr layout (ints): [8..15]=cnt_x, [16..23]=cnt_y, [24..31]=fill_x, [32..39]=fill_y
struct Params {
  const float* x; const float* centers; const float* ftarg;
  const float* y; const int* predy;
  float* out;
  int* zr;
  int* pred_x;
  int* cntx; int* cnty; int* off_x; int* off_y;
  int* bxy; int* byx; int* bxx; int* byy;    // per-cluster segment bases in Call
  int* tpre;                                 // 33-entry tile prefix table
  float* la; float* lb; int* valid; float* acc;
  float* part;                               // 24 per-block partials
  int* cmax;                                 // 32 float-as-int per-segment maxima
  float* Xp; float* Yp; float* xn; float* yn;
  float* Call;
};

__device__ __forceinline__ float wredsum(float v){
  #pragma unroll
  for(int m=32;m>=1;m>>=1) v += __shfl_xor(v,m,64);
  return v;
}
__device__ __forceinline__ float wredmax(float v){
  #pragma unroll
  for(int m=32;m>=1;m>>=1) v = fmaxf(v, __shfl_xor(v,m,64));
  return v;
}

// ---------------- k_pred: zero part/cmax + kmeans predict + LDS-hist counts ----------------
__global__ void __launch_bounds__(256) k_pred(Params p){
  __shared__ int hx[KC], hy[KC];
  const int tid = threadIdx.x;
  const int gtid = blockIdx.x*blockDim.x + tid;
  const int nth  = gridDim.x*blockDim.x;

  if(tid<KC){ hx[tid]=0; hy[tid]=0; }
  __syncthreads();

  for(int i=gtid;i<32;i+=nth) p.cmax[i]=0;
  for(int i=gtid;i<24;i+=nth) p.part[i]=0.f;

  for(int i=gtid;i<NN;i+=nth){
    const float4* xi = (const float4*)(p.x + i*DD);
    float best = 3.4e38f; int bk = 0;
    for(int k=0;k<KC;k++){
      const float4* ck = (const float4*)(p.centers + k*DD);
      float s = 0.f;
      #pragma unroll
      for(int q=0;q<DD/4;q++){ float4 a=xi[q], b=ck[q];
        float dx=a.x-b.x, dy=a.y-b.y, dz=a.z-b.z, dw=a.w-b.w;
        s += dx*dx+dy*dy+dz*dz+dw*dw; }
      if(s < best){ best = s; bk = k; }
    }
    p.pred_x[i] = bk;
    atomicAdd(&hx[bk], 1);
  }
  for(int j=gtid;j<MM;j+=nth) atomicAdd(&hy[p.predy[j]], 1);
  __syncthreads();
  if(tid<KC   && hx[tid])    atomicAdd(&p.zr[8+tid], hx[tid]);
  if(tid>=KC && tid<2*KC && hy[tid-KC]) atomicAdd(&p.zr[16+tid-KC], hy[tid-KC]);
}

// ---------------- k_pack: redundant serial phase + block-reserved pack ----------------
__global__ void __launch_bounds__(256) k_pack(Params p){
  __shared__ int scx[KC], scy[KC];
  __shared__ int sox[KC+1], soy[KC+1];
  __shared__ int hbx[KC], hby[KC], basex[KC], basey[KC], curx[KC], cury[KC];
  const int tid = threadIdx.x;
  const int gtid = blockIdx.x*blockDim.x + tid;
  const int nth  = gridDim.x*blockDim.x;

  if(tid==0){
    int ox=0, oy=0; float lf=0.f;
    int sbxy[KC], sbyx[KC], sbxx[KC], sbyy[KC];
    for(int k=0;k<KC;k++){
      int nk=p.zr[8+k], mk=p.zr[16+k];
      scx[k]=nk; scy[k]=mk;
      sox[k]=ox; soy[k]=oy;
      ox+=nk; oy+=mk;
      float df = (float)nk/(float)NN - p.ftarg[k];
      lf += df*df;
    }
    sox[KC]=ox; soy[KC]=oy;
    int run=0;
    for(int k=0;k<KC;k++){ int nk=scx[k], mk=scy[k]; sbxy[k]=run; run+=nk*RUP(mk); }
    for(int k=0;k<KC;k++){ int nk=scx[k], mk=scy[k]; sbyx[k]=run; run+=mk*RUP(nk); }
    for(int k=0;k<KC;k++){ int nk=scx[k];            sbxx[k]=run; run+=nk*RUP(nk); }
    for(int k=0;k<KC;k++){ int mk=scy[k];            sbyy[k]=run; run+=mk*RUP(mk); }
    if(blockIdx.x==0){
      for(int k=0;k<KC;k++){
        int nk=scx[k], mk=scy[k];
        p.cntx[k]=nk; p.cnty[k]=mk;
        p.off_x[k]=sox[k]; p.off_y[k]=soy[k];
        p.bxy[k]=sbxy[k]; p.byx[k]=sbyx[k]; p.bxx[k]=sbxx[k]; p.byy[k]=sbyy[k];
        p.la[k] = -logf(fmaxf((float)nk,1.f));
        p.lb[k] = -logf(fmaxf((float)mk,1.f));
        p.valid[k] = (nk>0 && mk>0)?1:0;
      }
      int trun=0;
      for(int e=0;e<32;e++){
        int seg=e>>3, k=e&7;
        int nk=scx[k], mk=scy[k];
        int nrows = (seg==0)?nk:(seg==1)?mk:(seg==2)?nk:mk;
        int rs    = (seg==0)?RUP(mk):(seg==1)?RUP(nk):(seg==2)?RUP(nk):RUP(mk);
        p.tpre[e]=trun;
        trun += ((nrows+63)>>6) * ((rs+63)>>6);
      }
      p.tpre[32]=trun;
      *p.acc = lf/(float)KC;
    }
  }
  if(tid<KC){ hbx[tid]=0; hby[tid]=0; curx[tid]=0; cury[tid]=0; }
  __syncthreads();

  for(int i=gtid;i<NN;i+=nth) atomicAdd(&hbx[p.pred_x[i]],1);
  for(int j=gtid;j<MM;j+=nth) atomicAdd(&hby[p.predy[j]],1);
  __syncthreads();
  if(tid<KC){
    basex[tid] = sox[tid] + (hbx[tid] ? atomicAdd(&p.zr[24+tid], hbx[tid]) : 0);
    basey[tid] = soy[tid] + (hby[tid] ? atomicAdd(&p.zr[32+tid], hby[tid]) : 0);
  }
  __syncthreads();

  for(int i=gtid;i<NN;i+=nth){
    int k=p.pred_x[i];
    int pos = basex[k] + atomicAdd(&curx[k],1);
    const float4* xi=(const float4*)(p.x+i*DD);
    float4* dst=(float4*)(p.Xp+(size_t)pos*DD);
    float s=0.f;
    #pragma unroll
    for(int q=0;q<DD/4;q++){ float4 v=xi[q]; dst[q]=v;
      s += v.x*v.x+v.y*v.y+v.z*v.z+v.w*v.w; }
    p.xn[pos]=s;
  }
  for(int j=gtid;j<MM;j+=nth){
    int k=p.predy[j];
    int pos = basey[k] + atomicAdd(&cury[k],1);
    const float4* yj=(const float4*)(p.y+j*DD);
    float4* dst=(float4*)(p.Yp+(size_t)pos*DD);
    float s=0.f;
    #pragma unroll
    for(int q=0;q<DD/4;q++){ float4 v=yj[q]; dst[q]=v;
      s += v.x*v.x+v.y*v.y+v.z*v.z+v.w*v.w; }
    p.yn[pos]=s;
  }
}

// ---------------- k4: LDS-tiled cost build + per-segment max (for quantization) ----------------
__global__ void __launch_bounds__(256) k4_cost(Params p){
  __shared__ float As[64*68];
  __shared__ float Bt[64*68];
  const int tid = threadIdx.x;
  const int T = p.tpre[32];

  for(int tile=blockIdx.x; tile<T; tile+=gridDim.x){
    int e=0;
    for(int q=1;q<32;q++) if(tile>=p.tpre[q]) e=q;
    int seg=e>>3, k=e&7;
    int nk=p.cntx[k], mk=p.cnty[k];
    int rsx=RUP(nk), rsy=RUP(mk);
    const float *Apts, *Bpts, *nA, *nB; int nrows, ncol, rs, base;
    if(seg==0){ Apts=p.Xp+(size_t)p.off_x[k]*DD; Bpts=p.Yp+(size_t)p.off_y[k]*DD;
      nA=p.xn+p.off_x[k]; nB=p.yn+p.off_y[k]; nrows=nk; ncol=mk; rs=rsy; base=p.bxy[k]; }
    else if(seg==1){ Apts=p.Yp+(size_t)p.off_y[k]*DD; Bpts=p.Xp+(size_t)p.off_x[k]*DD;
      nA=p.yn+p.off_y[k]; nB=p.xn+p.off_x[k]; nrows=mk; ncol=nk; rs=rsx; base=p.byx[k]; }
    else if(seg==2){ Apts=p.Xp+(size_t)p.off_x[k]*DD; Bpts=Apts;
      nA=p.xn+p.off_x[k]; nB=nA; nrows=nk; ncol=nk; rs=rsx; base=p.bxx[k]; }
    else { Apts=p.Yp+(size_t)p.off_y[k]*DD; Bpts=Apts;
      nA=p.yn+p.off_y[k]; nB=nA; nrows=mk; ncol=mk; rs=rsy; base=p.byy[k]; }
    int ntc=(rs+63)>>6;
    int lt = tile - p.tpre[e];
    int tr = lt/ntc, tc = lt - tr*ntc;

    __syncthreads();
    for(int l=tid;l<1024;l+=256){
      int row=l>>4, c4=l&15;
      int gA=tr*64+row;
      float4 va = (gA<nrows)? ((const float4*)Apts)[gA*16+c4] : make_float4(0.f,0.f,0.f,0.f);
      *(float4*)&As[row*68 + c4*4] = va;
      int gB=tc*64+row;
      float4 vb = (gB<ncol)? ((const float4*)Bpts)[gB*16+c4] : make_float4(0.f,0.f,0.f,0.f);
      Bt[(c4*4+0)*68+row]=vb.x; Bt[(c4*4+1)*68+row]=vb.y;
      Bt[(c4*4+2)*68+row]=vb.z; Bt[(c4*4+3)*68+row]=vb.w;
    }
    __syncthreads();

    int tx=tid&15, ty=tid>>4;
    float4 acc[4] = {make_float4(0,0,0,0),make_float4(0,0,0,0),
                     make_float4(0,0,0,0),make_float4(0,0,0,0)};
    for(int kk=0;kk<64;kk+=4){
      float4 a0=*(float4*)&As[(ty*4+0)*68+kk];
      float4 a1=*(float4*)&As[(ty*4+1)*68+kk];
      float4 a2=*(float4*)&As[(ty*4+2)*68+kk];
      float4 a3=*(float4*)&As[(ty*4+3)*68+kk];
      float4 b0=*(float4*)&Bt[(kk+0)*68+tx*4];
      float4 b1=*(float4*)&Bt[(kk+1)*68+tx*4];
      float4 b2=*(float4*)&Bt[(kk+2)*68+tx*4];
      float4 b3=*(float4*)&Bt[(kk+3)*68+tx*4];
      #define ACCROW(i,AI) \
        acc[i].x = fmaf(AI.x,b0.x, fmaf(AI.y,b1.x, fmaf(AI.z,b2.x, fmaf(AI.w,b3.x, acc[i].x)))); \
        acc[i].y = fmaf(AI.x,b0.y, fmaf(AI.y,b1.y, fmaf(AI.z,b2.y, fmaf(AI.w,b3.y, acc[i].y)))); \
        acc[i].z = fmaf(AI.x,b0.z, fmaf(AI.y,b1.z, fmaf(AI.z,b2.z, fmaf(AI.w,b3.z, acc[i].z)))); \
        acc[i].w = fmaf(AI.x,b0.w, fmaf(AI.y,b1.w, fmaf(AI.z,b2.w, fmaf(AI.w,b3.w, acc[i].w))));
      ACCROW(0,a0) ACCROW(1,a1) ACCROW(2,a2) ACCROW(3,a3)
      #undef ACCROW
    }

    int gc0 = tc*64 + tx*4;
    float lmax = 0.f;
    #pragma unroll
    for(int i=0;i<4;i++){
      int gr = tr*64 + ty*4 + i;
      if(gr >= nrows) continue;
      float xr = nA[gr];
      float v[4]; float d[4]={acc[i].x,acc[i].y,acc[i].z,acc[i].w};
      #pragma unroll
      for(int j=0;j<4;j++){
        int gc = gc0+j;
        v[j] = PADV;
        if(gc < ncol){ v[j] = 0.5f*fmaxf(xr + nB[gc] - 2.f*d[j], 0.f);
                       lmax = fmaxf(lmax, v[j]); }
      }
      if(gc0+3 < rs){
        *(float4*)&p.Call[(size_t)base + (size_t)gr*rs + gc0] = make_float4(v[0],v[1],v[2],v[3]);
      } else {
        for(int j=0;j<4;j++) if(gc0+j < rs) p.Call[(size_t)base + (size_t)gr*rs + gc0+j] = v[j];
      }
    }
    lmax = wredmax(lmax);
    if((tid&63)==0 && lmax>0.f) atomicMax(&p.cmax[e], __float_as_int(lmax));
  }
}

// 8-wide online-LSE step (base-2): w0..w7 prepared by caller
#define LSE8(m,s) { \
  float lm=fmaxf(fmaxf(fmaxf(w0,w1),fmaxf(w2,w3)),fmaxf(fmaxf(w4,w5),fmaxf(w6,w7))); \
  if(lm >= m-30.f){ \
    float mn=fmaxf(m,lm); \
    s = s*exp2f(m-mn) + ((exp2f(w0-mn)+exp2f(w1-mn))+(exp2f(w2-mn)+exp2f(w3-mn))) \
                      + ((exp2f(w4-mn)+exp2f(w5-mn))+(exp2f(w6-mn)+exp2f(w7-mn))); \
    m = mn; } }
#define LSE4W(m,s) { \
  float lm=fmaxf(fmaxf(w0,w1),fmaxf(w2,w3)); \
  if(lm >= m-30.f){ \
    float mn=fmaxf(m,lm); \
    s = s*exp2f(m-mn) + (exp2f(w0-mn)+exp2f(w1-mn)) + (exp2f(w2-mn)+exp2f(w3-mn)); \
    m = mn; } }

// ---------------- k_clust: whole Sinkhorn chain per cluster-job, in-LDS ----------------
// 24 blocks = {xy, xx, yy} x 8 clusters, 1024 threads each. ALL iteration state
// (int8 row-quantized C + potentials + P2 tables) lives in LDS; the only
// barrier is __syncthreads. Row-quant: C_ij ~ off_r + q*scl_r. Fold:
//   w_true = P2c - C*s1 = (P2c - q*scl*s1) - off*s1  =>  LSE_true = LSE' - off*s1
// so the row update is ft = -eps*ln2*((m' - off*s1) + log2 S).   [r7 bug: +off]
// Column scan folds off into P2r[i] = (f_i - off_i)*s1 + h (subtracted there).
// Fallback (Q too big for LDS): stream fp32 C from global, coalesced.
__global__ void __launch_bounds__(1024, 1) k_clust(Params p, int dynB){
  extern __shared__ char dyn[];
  __shared__ float red[16];
  const int tid=threadIdx.x, lane=tid&63, wv=tid>>6;
  const int jt=blockIdx.x>>3, k=blockIdx.x&7;
  if(!p.valid[k]){ if(tid==0) p.part[blockIdx.x]=0.f; return; }

  const int nk=p.cntx[k], mk=p.cnty[k];
  const float la2=p.la[k]*INVLN2F, lb2=p.lb[k]*INVLN2F;

  int R1, Creal; const float* seg1; float hcol, fva;
  const float* seg2=nullptr; int R2=0; float hrow=0.f, fvb=0.f;
  if(jt==0){ R1=nk; Creal=mk; seg1=p.Call+p.bxy[k]; hcol=lb2; fva= 1.f/(float)nk;
             R2=mk; seg2=p.Call+p.byx[k]; hrow=la2; fvb= 1.f/(float)mk; }
  else if(jt==1){ R1=nk; Creal=nk; seg1=p.Call+p.bxx[k]; hcol=la2; fva=-1.f/(float)nk; }
  else          { R1=mk; Creal=mk; seg1=p.Call+p.byy[k]; hcol=lb2; fva=-1.f/(float)mk; }
  const int NR=RUP(R1), CC=RUP(Creal);
  const int pad = (48 - (CC & 127) + 128) & 127;   // row stride ≡48 mod 128 -> bank spread
  const int mkp = CC + pad;
  const int CQ = CC/4, IQ = NR/4;

  // LDS partition (pots always; row tables + Q only if they fit)
  char* q_ = dyn;
  auto al=[&](size_t b)->char*{ char* r=q_; q_ += (b+15)&~(size_t)15; return r; };
  float* A0=(float*)al((size_t)NR*4); float* A1=(float*)al((size_t)NR*4);
  float *B0=nullptr,*B1=nullptr,*P2r=nullptr,*M1r=nullptr;
  if(jt==0){ B0=(float*)al((size_t)CC*4); B1=(float*)al((size_t)CC*4);
             P2r=(float*)al((size_t)NR*4); M1r=(float*)al((size_t)NR*4); }
  float* P2c=(float*)al((size_t)CC*4);
  size_t used = (size_t)(q_-dyn);
  const size_t need = 2*(size_t)NR*4 + (size_t)NR*mkp + 64;
  const bool fits = (used + need) <= (size_t)dynB;
  float *roff=nullptr,*rscl=nullptr; unsigned char* Q=nullptr;
  if(fits){ roff=(float*)al((size_t)NR*4); rscl=(float*)al((size_t)NR*4);
            Q=(unsigned char*)al((size_t)NR*mkp); }

  for(int i=tid;i<NR;i+=1024){ A0[i]=0.f; A1[i]=0.f; }
  if(jt==0) for(int c=tid;c<CC;c+=1024){ B0[c]=0.f; B1[c]=0.f; }

  if(fits){
    // pass A: per-row min/max (finite entries only); 4 lanes/row
    for(int r0=0;r0<R1;r0+=256){
      int r=r0+(tid>>2), sub=tid&3;
      float mn=3.4e38f, mx=0.f;
      if(r<R1){
        const float* row=seg1+(size_t)r*CC;
        for(int c=sub*CQ;c<sub*CQ+CQ;c+=4){
          float4 v=*(const float4*)(row+c);
          if(v.x<1e30f){ mn=fminf(mn,v.x); mx=fmaxf(mx,v.x); }
          if(v.y<1e30f){ mn=fminf(mn,v.y); mx=fmaxf(mx,v.y); }
          if(v.z<1e30f){ mn=fminf(mn,v.z); mx=fmaxf(mx,v.z); }
          if(v.w<1e30f){ mn=fminf(mn,v.w); mx=fmaxf(mx,v.w); }
        }
        #pragma unroll
        for(int msk=1;msk<4;msk<<=1){
          mn=fminf(mn,__shfl_xor(mn,msk,64));
          mx=fmaxf(mx,__shfl_xor(mx,msk,64));
        }
        if(sub==0){ roff[r]=mn; rscl[r]=fmaxf((mx-mn)*(1.f/254.f),1e-12f); }
      }
    }
    __syncthreads();
    // pass B: quantize q = clamp(round((C-off)/scl),0,255); PADV -> 255
    const int CC8=CC/8;
    for(int idx=tid; idx<R1*CC8; idx+=1024){
      int r=idx/CC8, c0=(idx-r*CC8)*8;
      const float* row=seg1+(size_t)r*CC;
      float off=roff[r], inv=1.f/rscl[r];
      float4 a=*(const float4*)(row+c0), b=*(const float4*)(row+c0+4);
      unsigned q0=(unsigned)fminf(fmaxf((a.x-off)*inv+0.5f,0.f),255.f);
      unsigned q1=(unsigned)fminf(fmaxf((a.y-off)*inv+0.5f,0.f),255.f);
      unsigned q2=(unsigned)fminf(fmaxf((a.z-off)*inv+0.5f,0.f),255.f);
      unsigned q3=(unsigned)fminf(fmaxf((a.w-off)*inv+0.5f,0.f),255.f);
      unsigned q4=(unsigned)fminf(fmaxf((b.x-off)*inv+0.5f,0.f),255.f);
      unsigned q5=(unsigned)fminf(fmaxf((b.y-off)*inv+0.5f,0.f),255.f);
      unsigned q6=(unsigned)fminf(fmaxf((b.z-off)*inv+0.5f,0.f),255.f);
      unsigned q7=(unsigned)fminf(fmaxf((b.w-off)*inv+0.5f,0.f),255.f);
      *(uint2*)(Q+(size_t)r*mkp+c0) =
        make_uint2(q0|(q1<<8)|(q2<<16)|(q3<<24), q4|(q5<<8)|(q6<<16)|(q7<<24));
    }
  }
  __syncthreads();

  const double EMIND = 0.05*0.05, S2D = 0.8*0.8;

  // one Jacobi pass (or final extrapolation when fin=true)
  auto pass = [&](float eps, float s1, bool fin,
                  const float* Ac, float* An, const float* Bc, float* Bn,
                  float& contrib){
    // P2 tables from current potentials
    const float* colsrc = (jt==0)? Bc : Ac;
    for(int c=tid;c<CC;c+=1024)
      P2c[c] = (c<Creal)? fmaf(colsrc[c],s1,hcol) : -1e30f;
    if(jt==0)
      for(int i=tid;i<NR;i+=1024){
        if(i<R1){
          if(fits){ P2r[i]=fmaf(Ac[i]-roff[i],s1,hrow); M1r[i]=-rscl[i]*s1; }
          else    { P2r[i]=fmaf(Ac[i],s1,hrow); M1r[i]=0.f; }
        } else { P2r[i]=-1e30f; M1r[i]=0.f; }
      }
    __syncthreads();

    // scan 1: rows of C (f / faa / gbb update)
    for(int r0=0;r0<R1;r0+=256){
      int r=r0+(tid>>2), sub=tid&3;
      if(r<R1){
        float m=-3.4e38f, s=0.f, rb=0.f;
        if(fits){
          float nrs=-rscl[r]*s1; rb=roff[r]*s1;
          const unsigned char* Qr=Q+(size_t)r*mkp;
          for(int c=sub*CQ;c<sub*CQ+CQ;c+=8){
            uint2 d=*(const uint2*)(Qr+c);
            float4 pA=*(const float4*)&P2c[c], pB=*(const float4*)&P2c[c+4];
            float w0=fmaf((float)( d.x      &255u),nrs,pA.x);
            float w1=fmaf((float)((d.x>> 8) &255u),nrs,pA.y);
            float w2=fmaf((float)((d.x>>16) &255u),nrs,pA.z);
            float w3=fmaf((float)( d.x>>24       ),nrs,pA.w);
            float w4=fmaf((float)( d.y      &255u),nrs,pB.x);
            float w5=fmaf((float)((d.y>> 8) &255u),nrs,pB.y);
            float w6=fmaf((float)((d.y>>16) &255u),nrs,pB.z);
            float w7=fmaf((float)( d.y>>24       ),nrs,pB.w);
            LSE8(m,s)
          }
        } else {
          const float* row=seg1+(size_t)r*CC;
          for(int c=sub*CQ;c<sub*CQ+CQ;c+=4){
            float4 cv=*(const float4*)(row+c);
            float4 pA=*(const float4*)&P2c[c];
            float w0=fmaf(cv.x,-s1,pA.x), w1=fmaf(cv.y,-s1,pA.y);
            float w2=fmaf(cv.z,-s1,pA.z), w3=fmaf(cv.w,-s1,pA.w);
            LSE4W(m,s)
          }
        }
        #pragma unroll
        for(int msk=1;msk<4;msk<<=1){
          float om=__shfl_xor(m,msk,64), os=__shfl_xor(s,msk,64);
          float mn=fmaxf(m,om);
          s = s*exp2f(m-mn) + os*exp2f(om-mn);
          m = mn;
        }
        if(sub==0){
          // LSE_true = LSE' - off*s1  (row-quant offset shift, SUBTRACTED)
          float ft = -eps*LN2F*((m - rb) + log2f(s));
          if(fin) contrib += fva*ft;
          else    An[r] = 0.5f*(Ac[r] + ft);
        }
      }
    }

    // scan 2 (xy only): columns of C (g update)
    if(jt==0){
      for(int j0=0;j0<R2;j0+=256){
        int j=j0+(tid>>2), q4=tid&3;
        if(j<R2){
          float m=-3.4e38f, s=0.f;
          if(fits){
            for(int i=q4*IQ;i<q4*IQ+IQ;i+=8){
              const unsigned char* Qc=Q+(size_t)i*mkp+j;
              float g0=(float)Qc[0],            g1=(float)Qc[(size_t)mkp];
              float g2=(float)Qc[(size_t)2*mkp],g3=(float)Qc[(size_t)3*mkp];
              float g4=(float)Qc[(size_t)4*mkp],g5=(float)Qc[(size_t)5*mkp];
              float g6=(float)Qc[(size_t)6*mkp],g7=(float)Qc[(size_t)7*mkp];
              float4 pA=*(const float4*)&P2r[i], pB=*(const float4*)&P2r[i+4];
              float4 sA=*(const float4*)&M1r[i], sB=*(const float4*)&M1r[i+4];
              float w0=fmaf(g0,sA.x,pA.x), w1=fmaf(g1,sA.y,pA.y);
              float w2=fmaf(g2,sA.z,pA.z), w3=fmaf(g3,sA.w,pA.w);
              float w4=fmaf(g4,sB.x,pB.x), w5=fmaf(g5,sB.y,pB.y);
              float w6=fmaf(g6,sB.z,pB.z), w7=fmaf(g7,sB.w,pB.w);
              LSE8(m,s)
            }
          } else {
            const float* row2=seg2+(size_t)j*NR;
            for(int i=q4*IQ;i<q4*IQ+IQ;i+=4){
              float4 cv=*(const float4*)(row2+i);
              float4 pA=*(const float4*)&P2r[i];
              float w0=fmaf(cv.x,-s1,pA.x), w1=fmaf(cv.y,-s1,pA.y);
              float w2=fmaf(cv.z,-s1,pA.z), w3=fmaf(cv.w,-s1,pA.w);
              LSE4W(m,s)
            }
          }
          #pragma unroll
          for(int msk=1;msk<4;msk<<=1){
            float om=__shfl_xor(m,msk,64), os=__shfl_xor(s,msk,64);
            float mn=fmaxf(m,om);
            s = s*exp2f(m-mn) + os*exp2f(om-mn);
            m = mn;
          }
          if(q4==0){
            float gt = -eps*LN2F*(m + log2f(s));
            if(fin) contrib += fvb*gt;
            else    Bn[j] = 0.5f*(Bc[j] + gt);
          }
        }
      }
    }
    __syncthreads();   // writes visible / P2 reusable next pass
  };

  // eps-scaling loop (schedule identical to reference)
  double e = 16.0; int cur = 0; float dummy=0.f;
  for(;;){
    const bool last = !(e > EMIND);
    const float eps = last ? (float)EMIND : (float)e;
    const float s1 = (1.0f/eps)*INVLN2F;
    pass(eps, s1, false,
         cur?A1:A0, cur?A0:A1,
         (jt==0)?(cur?B1:B0):nullptr, (jt==0)?(cur?B0:B1):nullptr, dummy);
    cur ^= 1;
    if(last) break;
    e *= S2D;
  }

  // final extrapolation at eps_min with post-loop potentials
  float contrib = 0.f;
  {
    const float eps = (float)EMIND;
    const float s1 = (1.0f/eps)*INVLN2F;
    pass(eps, s1, true,
         cur?A1:A0, nullptr,
         (jt==0)?(cur?B1:B0):nullptr, nullptr, contrib);
  }
  contrib = wredsum(contrib);
  if(lane==0) red[wv] = contrib;
  __syncthreads();
  if(wv==0){
    float v = (lane<16)? red[lane] : 0.f;
    v = wredsum(v);
    if(lane==0) p.part[blockIdx.x] = v;
  }
}

// ---------------- k_out: sum 24 partials + filling loss ----------------
__global__ void __launch_bounds__(64) k_out(Params p){
  float s = (threadIdx.x<24)? p.part[threadIdx.x] : 0.f;
  s = wredsum(s);
  if(threadIdx.x==0) p.out[0] = s + *p.acc;
}

extern "C" void kernel_launch(void* const* d_in, const int* in_sizes, int n_in,
                              void* d_out, int out_size, void* d_ws, size_t ws_size,
                              hipStream_t stream)
{
  Params p;
  p.x       = (const float*)d_in[0];
  p.centers = (const float*)d_in[1];
  p.ftarg   = (const float*)d_in[2];
  p.y       = (const float*)d_in[3];
  p.predy   = (const int*)d_in[4];
  p.out     = (float*)d_out;

  char* w = (char*)d_ws; size_t o = 0;
  auto A = [&](size_t bytes)->char*{ char* r = w + o; o = (o + bytes + 255) & ~(size_t)255; return r; };
  p.zr   =(int*)A(64*4);
  p.pred_x=(int*)A(NN*4);
  p.cntx =(int*)A(KC*4); p.cnty=(int*)A(KC*4);
  p.off_x=(int*)A(KC*4); p.off_y=(int*)A(KC*4);
  p.bxy  =(int*)A(KC*4); p.byx =(int*)A(KC*4);
  p.bxx  =(int*)A(KC*4); p.byy =(int*)A(KC*4);
  p.tpre =(int*)A(33*4);
  p.la=(float*)A(KC*4); p.lb=(float*)A(KC*4); p.valid=(int*)A(KC*4);
  p.acc=(float*)A(4);
  p.part=(float*)A(24*4);
  p.cmax=(int*)A(32*4);
  p.Xp=(float*)A((size_t)NN*DD*4); p.Yp=(float*)A((size_t)MM*DD*4);
  p.xn=(float*)A(NN*4); p.yn=(float*)A(MM*4);
  p.Call=(float*)A((size_t)CPAD*4);

  int dynb = DYNB;
  if(hipFuncSetAttribute((const void*)k_clust,
       hipFuncAttributeMaxDynamicSharedMemorySize, DYNB) != hipSuccess)
    dynb = DYNB_FALLBACK;

  hipMemsetAsync(p.zr, 0, 64*4, stream);
  hipLaunchKernelGGL(k_pred,  dim3(16),  dim3(256),  0, stream, p);
  hipLaunchKernelGGL(k_pack,  dim3(32),  dim3(256),  0, stream, p);
  hipLaunchKernelGGL(k4_cost, dim3(512), dim3(256),  0, stream, p);
  hipLaunchKernelGGL(k_clust, dim3(24),  dim3(1024), dynb, stream, p, dynb);
  hipLaunchKernelGGL(k_out,   dim3(1),   dim3(64),   0, stream, p);
}